// Round 5
// baseline (170.698 us; speedup 1.0000x reference)
//
#include <hip/hip_runtime.h>
#include <math.h>

#define B_DIM 256
#define M_DIM 4096
#define EPSV 1e-7f
#define THREADS 1024
#define ROW_F4 (M_DIM * 9 / 4)   // 9216 float4 per row per array

// ws layout (floats):
//   [0      .. 2048)  per-row-block partials: 256 blocks x 8 {coord,width,val,nval,cont,-,-,-}
//   [2048   .. 4096)  recon per-block partials: 2048 floats

__global__ __launch_bounds__(THREADS, 4) void row_loss_kernel(
    const float4* __restrict__ pred4, const float4* __restrict__ tgt4,
    float* __restrict__ blk_out)
{
    __shared__ float s_p4[M_DIM];                      // 16 KB
    __shared__ float s_p5[M_DIM];                      // 16 KB
    __shared__ unsigned char s_valid[M_DIM];           // 4 KB
    __shared__ unsigned long long s_words[M_DIM / 64]; // 512 B
    __shared__ float s_red[16][5];

    const int b    = blockIdx.x;
    const int t    = threadIdx.x;
    const int lane = t & 63;
    const int wave = t >> 6;

    const float4* pb = pred4 + (size_t)b * ROW_F4;
    const float4* tb = tgt4  + (size_t)b * ROW_F4;

    // ---- fully coalesced loads: lane-contiguous 16B per lane per instruction ----
    float4 pr[9], tr[9];
    #pragma unroll
    for (int i = 0; i < 9; ++i) pr[i] = pb[i * THREADS + t];
    #pragma unroll
    for (int i = 0; i < 9; ++i) tr[i] = tb[i * THREADS + t];

    // ---- phase 1: extraction scatter + BCE (computed by c==8 holders) ----
    float val_s = 0.f, nval_s = 0.f;
    #pragma unroll
    for (int i = 0; i < 9; ++i) {
        int j0 = 4 * (i * THREADS + t);
        unsigned m = (unsigned)j0 / 9u;     // magic-mul division
        int c = j0 - 9 * (int)m;
        float pe[4] = {pr[i].x, pr[i].y, pr[i].z, pr[i].w};
        float te[4] = {tr[i].x, tr[i].y, tr[i].z, tr[i].w};
        #pragma unroll
        for (int k = 0; k < 4; ++k) {
            if (c == 4)      s_p4[m] = pe[k];
            else if (c == 5) s_p5[m] = pe[k];
            else if (c == 8) {
                float t8 = te[k];
                bool valid = (t8 > 0.5f);
                s_valid[m] = valid ? 1 : 0;
                nval_s += valid ? 1.f : 0.f;
                float pc = fminf(fmaxf(pe[k], EPSV), 1.0f - EPSV);
                val_s += -(t8 * __logf(pc) + (1.0f - t8) * __logf(1.0f - pc));
            }
            ++c; if (c == 9) { c = 0; ++m; }
        }
        // keep only |p - t| live across the barrier (halves register pressure)
        pr[i].x = fabsf(pe[0] - te[0]);
        pr[i].y = fabsf(pe[1] - te[1]);
        pr[i].z = fabsf(pe[2] - te[2]);
        pr[i].w = fabsf(pe[3] - te[3]);
    }
    __syncthreads();

    // ---- build validity bitmask words from s_valid (for continuity) ----
    #pragma unroll
    for (int p = 0; p < 4; ++p) {
        bool v = s_valid[p * 1024 + t] != 0;
        unsigned long long w = __ballot(v);
        if (lane == 0) s_words[p * 16 + wave] = w;
    }

    // ---- phase 2: masked L1 from register-held |p-t| ----
    float coord_s = 0.f, width_s = 0.f;
    #pragma unroll
    for (int i = 0; i < 9; ++i) {
        int j0 = 4 * (i * THREADS + t);
        unsigned m = (unsigned)j0 / 9u;
        int c = j0 - 9 * (int)m;
        float ad[4] = {pr[i].x, pr[i].y, pr[i].z, pr[i].w};
        #pragma unroll
        for (int k = 0; k < 4; ++k) {
            float fm = (float)s_valid[m];
            if (c < 6)      coord_s += fm * ad[k];
            else if (c < 8) width_s += fm * ad[k];
            ++c; if (c == 9) { c = 0; ++m; }
        }
    }
    __syncthreads();   // s_words complete before scan

    // ---- continuity: next-valid bit-scan ----
    float cont_s = 0.f;
    #pragma unroll
    for (int p = 0; p < 4; ++p) {
        const int m   = p * 1024 + t;
        const int w   = m >> 6;
        const int bit = m & 63;
        unsigned long long wv = s_words[w];
        if ((wv >> bit) & 1ULL) {
            unsigned long long mask = wv & ((bit == 63) ? 0ULL : (~0ULL << (bit + 1)));
            int nxt = -1;
            if (mask) {
                nxt = (w << 6) + __builtin_ctzll(mask);
            } else {
                for (int w2 = w + 1; w2 < (M_DIM / 64); ++w2) {
                    unsigned long long mw = s_words[w2];
                    if (mw) { nxt = (w2 << 6) + __builtin_ctzll(mw); break; }
                }
            }
            if (nxt >= 0) {
                cont_s += 0.5f * (fabsf(s_p4[m] - s_p4[nxt]) +
                                  fabsf(s_p5[m] - s_p5[nxt]));
            }
        }
    }

    // ---- block reduction; per-block slot write (no atomics) ----
    float vals[5] = {coord_s, width_s, val_s, nval_s, cont_s};
    #pragma unroll
    for (int i = 0; i < 5; ++i) {
        float v = vals[i];
        #pragma unroll
        for (int off = 32; off > 0; off >>= 1) v += __shfl_down(v, off, 64);
        vals[i] = v;
    }
    if (lane == 0) {
        #pragma unroll
        for (int i = 0; i < 5; ++i) s_red[wave][i] = vals[i];
    }
    __syncthreads();
    if (t == 0) {
        float acc[5] = {0.f, 0.f, 0.f, 0.f, 0.f};
        for (int wv = 0; wv < 16; ++wv)
            #pragma unroll
            for (int i = 0; i < 5; ++i) acc[i] += s_red[wv][i];
        float* r = blk_out + b * 8;
        #pragma unroll
        for (int i = 0; i < 5; ++i) r[i] = acc[i];
    }
}

__global__ __launch_bounds__(256) void recon_kernel(
    const float4* __restrict__ rec, const float4* __restrict__ img,
    float* __restrict__ blk_out)
{
    const int n4     = (B_DIM * 128 * 128) / 4;   // 1048576
    const int stride = gridDim.x * blockDim.x;    // 524288
    int idx = blockIdx.x * blockDim.x + threadIdx.x;
    float s = 0.f;
    for (int i = idx; i < n4; i += stride) {      // 2 iters
        float4 r = rec[i]; float4 m = img[i];
        float d0 = r.x - m.x, d1 = r.y - m.y, d2 = r.z - m.z, d3 = r.w - m.w;
        s += d0 * d0 + d1 * d1 + d2 * d2 + d3 * d3;
    }
    #pragma unroll
    for (int off = 32; off > 0; off >>= 1) s += __shfl_down(s, off, 64);
    __shared__ float sred[4];
    int lane = threadIdx.x & 63, wave = threadIdx.x >> 6;
    if (lane == 0) sred[wave] = s;
    __syncthreads();
    if (threadIdx.x == 0)
        blk_out[blockIdx.x] = sred[0] + sred[1] + sred[2] + sred[3];
}

__global__ __launch_bounds__(256) void finalize_kernel(
    const float* __restrict__ ws, float* __restrict__ out)
{
    const int t = threadIdx.x;
    const float* rb = ws + t * 8;
    float v[6];
    #pragma unroll
    for (int i = 0; i < 5; ++i) v[i] = rb[i];
    float rsum = 0.f;
    #pragma unroll
    for (int j = 0; j < 8; ++j) rsum += ws[2048 + t + 256 * j];
    v[5] = rsum;

    __shared__ float sred[4][6];
    int lane = t & 63, wave = t >> 6;
    #pragma unroll
    for (int i = 0; i < 6; ++i) {
        float x = v[i];
        #pragma unroll
        for (int off = 32; off > 0; off >>= 1) x += __shfl_down(x, off, 64);
        v[i] = x;
    }
    if (lane == 0)
        #pragma unroll
        for (int i = 0; i < 6; ++i) sred[wave][i] = v[i];
    __syncthreads();
    if (t == 0) {
        double a[6];
        #pragma unroll
        for (int i = 0; i < 6; ++i)
            a[i] = (double)sred[0][i] + (double)sred[1][i] +
                   (double)sred[2][i] + (double)sred[3][i];
        double coord_num = a[0], width_num = a[1], val_sum = a[2],
               nv = a[3], cont = a[4], recon = a[5];

        double coord = (nv > 0.0) ? coord_num / fmax(nv * 6.0, 1.0) : 0.0;
        double width = (nv > 0.0) ? width_num / fmax(nv * 2.0, 1.0) : 0.0;
        double validity = val_sum / ((double)B_DIM * (double)M_DIM);
        double contl    = cont / (double)B_DIM;
        double reconl   = recon / ((double)B_DIM * 128.0 * 128.0);

        out[0] = (float)(coord + width + 2.0 * validity +
                         0.2 * contl + 0.1 * reconl);
    }
}

extern "C" void kernel_launch(void* const* d_in, const int* in_sizes, int n_in,
                              void* d_out, int out_size, void* d_ws, size_t ws_size,
                              hipStream_t stream) {
    const float* pred = (const float*)d_in[0];
    const float* tgt  = (const float*)d_in[1];
    const float* rec  = (const float*)d_in[2];
    const float* img  = (const float*)d_in[3];
    float* ws = (float*)d_ws;

    // no memset needed: every ws slot read by finalize is written by a kernel first
    row_loss_kernel<<<B_DIM, THREADS, 0, stream>>>(
        (const float4*)pred, (const float4*)tgt, ws);
    recon_kernel<<<2048, 256, 0, stream>>>(
        (const float4*)rec, (const float4*)img, ws + 2048);
    finalize_kernel<<<1, 256, 0, stream>>>(ws, (float*)d_out);
}

// Round 6
// 135.397 us; speedup vs baseline: 1.2607x; 1.2607x over previous
//
#include <hip/hip_runtime.h>
#include <math.h>

#define B_DIM 256
#define M_DIM 4096
#define EPSV 1e-7f
#define THREADS 1024
#define CHUNK 1024
#define CHUNK_F4 (CHUNK * 9 / 4)   // 2304 float4 per array per chunk
#define NCHUNK (M_DIM / CHUNK)     // 4
#define ROW_F4 (M_DIM * 9 / 4)     // 9216

// ws layout (floats):
//   [0    .. 2048)  per-row-block partials: 256 blocks x 8 {coord,width,val,nval,cont}
//   [2048 .. 4096)  recon per-block partials: 2048 floats

__global__ __launch_bounds__(THREADS, 4) void row_loss_kernel(
    const float4* __restrict__ pred4, const float4* __restrict__ tgt4,
    float* __restrict__ blk_out)
{
    __shared__ float s_pred[CHUNK * 9];                // 36 KB stage
    __shared__ float s_tgt[CHUNK * 9];                 // 36 KB stage
    __shared__ float s_p4[M_DIM];                      // 16 KB
    __shared__ float s_p5[M_DIM];                      // 16 KB
    __shared__ unsigned long long s_words[M_DIM / 64]; // 512 B
    __shared__ float s_red[16][5];

    const int b    = blockIdx.x;
    const int t    = threadIdx.x;
    const int lane = t & 63;
    const int wave = t >> 6;

    const float4* pb = pred4 + (size_t)b * ROW_F4;
    const float4* tb = tgt4  + (size_t)b * ROW_F4;

    float coord_s = 0.f, width_s = 0.f, val_s = 0.f, nval_s = 0.f;

    for (int c = 0; c < NCHUNK; ++c) {
        const float4* pc = pb + c * CHUNK_F4;
        const float4* tc = tb + c * CHUNK_F4;

        if (c) __syncthreads();   // previous chunk fully consumed
        // ---- coalesced staging: lane-contiguous float4 loads -> LDS ----
        #pragma unroll
        for (int i = 0; i < 3; ++i) {
            int idx = i * THREADS + t;
            if (idx < CHUNK_F4) {
                ((float4*)s_pred)[idx] = pc[idx];
                ((float4*)s_tgt)[idx]  = tc[idx];
            }
        }
        __syncthreads();

        // ---- consume: thread t owns element (c*1024 + t) entirely ----
        const float* pe = s_pred + t * 9;   // stride 9 coprime to 32 banks
        const float* te = s_tgt  + t * 9;
        float p0 = pe[0], p1 = pe[1], p2 = pe[2], p3 = pe[3], p4 = pe[4],
              p5 = pe[5], p6 = pe[6], p7 = pe[7], p8 = pe[8];
        float t0 = te[0], t1 = te[1], t2 = te[2], t3 = te[3], t4 = te[4],
              t5 = te[5], t6 = te[6], t7 = te[7], t8 = te[8];

        bool valid = (t8 > 0.5f);
        float fm = valid ? 1.f : 0.f;
        coord_s += fm * (fabsf(p0 - t0) + fabsf(p1 - t1) + fabsf(p2 - t2) +
                         fabsf(p3 - t3) + fabsf(p4 - t4) + fabsf(p5 - t5));
        width_s += fm * (fabsf(p6 - t6) + fabsf(p7 - t7));
        nval_s  += fm;

        float pc8 = fminf(fmaxf(p8, EPSV), 1.0f - EPSV);
        val_s += -(t8 * __logf(pc8) + (1.0f - t8) * __logf(1.0f - pc8));

        const int m = c * CHUNK + t;
        s_p4[m] = p4;
        s_p5[m] = p5;
        unsigned long long bal = __ballot(valid);
        if (lane == 0) s_words[c * 16 + wave] = bal;
    }
    __syncthreads();

    // ---- continuity: next-valid bit-scan over full row ----
    float cont_s = 0.f;
    #pragma unroll
    for (int p = 0; p < 4; ++p) {
        const int m   = p * 1024 + t;
        const int w   = m >> 6;
        const int bit = m & 63;
        unsigned long long wv = s_words[w];
        if ((wv >> bit) & 1ULL) {
            unsigned long long mask = wv & ((bit == 63) ? 0ULL : (~0ULL << (bit + 1)));
            int nxt = -1;
            if (mask) {
                nxt = (w << 6) + __builtin_ctzll(mask);
            } else {
                for (int w2 = w + 1; w2 < (M_DIM / 64); ++w2) {
                    unsigned long long mw = s_words[w2];
                    if (mw) { nxt = (w2 << 6) + __builtin_ctzll(mw); break; }
                }
            }
            if (nxt >= 0) {
                cont_s += 0.5f * (fabsf(s_p4[m] - s_p4[nxt]) +
                                  fabsf(s_p5[m] - s_p5[nxt]));
            }
        }
    }

    // ---- block reduction; per-block slot write (no atomics) ----
    float vals[5] = {coord_s, width_s, val_s, nval_s, cont_s};
    #pragma unroll
    for (int i = 0; i < 5; ++i) {
        float v = vals[i];
        #pragma unroll
        for (int off = 32; off > 0; off >>= 1) v += __shfl_down(v, off, 64);
        vals[i] = v;
    }
    if (lane == 0) {
        #pragma unroll
        for (int i = 0; i < 5; ++i) s_red[wave][i] = vals[i];
    }
    __syncthreads();
    if (t == 0) {
        float acc[5] = {0.f, 0.f, 0.f, 0.f, 0.f};
        for (int wv = 0; wv < 16; ++wv)
            #pragma unroll
            for (int i = 0; i < 5; ++i) acc[i] += s_red[wv][i];
        float* r = blk_out + b * 8;
        #pragma unroll
        for (int i = 0; i < 5; ++i) r[i] = acc[i];
    }
}

__global__ __launch_bounds__(256) void recon_kernel(
    const float4* __restrict__ rec, const float4* __restrict__ img,
    float* __restrict__ blk_out)
{
    const int n4     = (B_DIM * 128 * 128) / 4;   // 1048576
    const int stride = gridDim.x * blockDim.x;    // 524288
    int idx = blockIdx.x * blockDim.x + threadIdx.x;
    float s = 0.f;
    for (int i = idx; i < n4; i += stride) {      // 2 iters
        float4 r = rec[i]; float4 m = img[i];
        float d0 = r.x - m.x, d1 = r.y - m.y, d2 = r.z - m.z, d3 = r.w - m.w;
        s += d0 * d0 + d1 * d1 + d2 * d2 + d3 * d3;
    }
    #pragma unroll
    for (int off = 32; off > 0; off >>= 1) s += __shfl_down(s, off, 64);
    __shared__ float sred[4];
    int lane = threadIdx.x & 63, wave = threadIdx.x >> 6;
    if (lane == 0) sred[wave] = s;
    __syncthreads();
    if (threadIdx.x == 0)
        blk_out[blockIdx.x] = sred[0] + sred[1] + sred[2] + sred[3];
}

__global__ __launch_bounds__(256) void finalize_kernel(
    const float* __restrict__ ws, float* __restrict__ out)
{
    const int t = threadIdx.x;
    const float* rb = ws + t * 8;
    float v[6];
    #pragma unroll
    for (int i = 0; i < 5; ++i) v[i] = rb[i];
    float rsum = 0.f;
    #pragma unroll
    for (int j = 0; j < 8; ++j) rsum += ws[2048 + t + 256 * j];
    v[5] = rsum;

    __shared__ float sred[4][6];
    int lane = t & 63, wave = t >> 6;
    #pragma unroll
    for (int i = 0; i < 6; ++i) {
        float x = v[i];
        #pragma unroll
        for (int off = 32; off > 0; off >>= 1) x += __shfl_down(x, off, 64);
        v[i] = x;
    }
    if (lane == 0)
        #pragma unroll
        for (int i = 0; i < 6; ++i) sred[wave][i] = v[i];
    __syncthreads();
    if (t == 0) {
        double a[6];
        #pragma unroll
        for (int i = 0; i < 6; ++i)
            a[i] = (double)sred[0][i] + (double)sred[1][i] +
                   (double)sred[2][i] + (double)sred[3][i];
        double coord_num = a[0], width_num = a[1], val_sum = a[2],
               nv = a[3], cont = a[4], recon = a[5];

        double coord = (nv > 0.0) ? coord_num / fmax(nv * 6.0, 1.0) : 0.0;
        double width = (nv > 0.0) ? width_num / fmax(nv * 2.0, 1.0) : 0.0;
        double validity = val_sum / ((double)B_DIM * (double)M_DIM);
        double contl    = cont / (double)B_DIM;
        double reconl   = recon / ((double)B_DIM * 128.0 * 128.0);

        out[0] = (float)(coord + width + 2.0 * validity +
                         0.2 * contl + 0.1 * reconl);
    }
}

extern "C" void kernel_launch(void* const* d_in, const int* in_sizes, int n_in,
                              void* d_out, int out_size, void* d_ws, size_t ws_size,
                              hipStream_t stream) {
    const float* pred = (const float*)d_in[0];
    const float* tgt  = (const float*)d_in[1];
    const float* rec  = (const float*)d_in[2];
    const float* img  = (const float*)d_in[3];
    float* ws = (float*)d_ws;

    row_loss_kernel<<<B_DIM, THREADS, 0, stream>>>(
        (const float4*)pred, (const float4*)tgt, ws);
    recon_kernel<<<2048, 256, 0, stream>>>(
        (const float4*)rec, (const float4*)img, ws + 2048);
    finalize_kernel<<<1, 256, 0, stream>>>(ws, (float*)d_out);
}

// Round 7
// 135.123 us; speedup vs baseline: 1.2633x; 1.0020x over previous
//
#include <hip/hip_runtime.h>
#include <math.h>

#define B_DIM 256
#define M_DIM 4096
#define EPSV 1e-7f
#define THREADS 1024
#define CHUNK 1024
#define CHUNK_F4 (CHUNK * 9 / 4)   // 2304 float4 per array per chunk
#define NCHUNK (M_DIM / CHUNK)     // 4
#define ROW_F4 (M_DIM * 9 / 4)     // 9216
#define RECON_F4_PER_BLOCK ((B_DIM * 128 * 128 / 4) / B_DIM)  // 4096

// ws layout (floats):
//   [0 .. 2048)  per-block partials: 256 blocks x 8 {coord,width,val,nval,cont,recon}

__global__ __launch_bounds__(THREADS, 4) void fused_loss_kernel(
    const float4* __restrict__ pred4, const float4* __restrict__ tgt4,
    const float4* __restrict__ rec4, const float4* __restrict__ img4,
    float* __restrict__ blk_out)
{
    __shared__ float s_pred[CHUNK * 9];                // 36 KB stage
    __shared__ float s_tgt[CHUNK * 9];                 // 36 KB stage
    __shared__ float s_p4[M_DIM];                      // 16 KB
    __shared__ float s_p5[M_DIM];                      // 16 KB
    __shared__ unsigned long long s_words[M_DIM / 64]; // 512 B
    __shared__ float s_red[16][6];

    const int b    = blockIdx.x;
    const int t    = threadIdx.x;
    const int lane = t & 63;
    const int wave = t >> 6;

    // ---- reconstruction MSE: this block's contiguous 1/256 slice ----
    float recon_s = 0.f;
    {
        const float4* rb = rec4 + (size_t)b * RECON_F4_PER_BLOCK;
        const float4* ib = img4 + (size_t)b * RECON_F4_PER_BLOCK;
        #pragma unroll
        for (int i = 0; i < RECON_F4_PER_BLOCK / THREADS; ++i) {   // 4 iters
            int idx = i * THREADS + t;
            float4 r = rb[idx]; float4 m = ib[idx];
            float d0 = r.x - m.x, d1 = r.y - m.y, d2 = r.z - m.z, d3 = r.w - m.w;
            recon_s += d0 * d0 + d1 * d1 + d2 * d2 + d3 * d3;
        }
    }

    const float4* pb = pred4 + (size_t)b * ROW_F4;
    const float4* tb = tgt4  + (size_t)b * ROW_F4;

    float coord_s = 0.f, width_s = 0.f, val_s = 0.f, nval_s = 0.f;

    for (int c = 0; c < NCHUNK; ++c) {
        const float4* pc = pb + c * CHUNK_F4;
        const float4* tc = tb + c * CHUNK_F4;

        if (c) __syncthreads();   // previous chunk fully consumed
        // ---- coalesced staging: lane-contiguous float4 loads -> LDS ----
        #pragma unroll
        for (int i = 0; i < 3; ++i) {
            int idx = i * THREADS + t;
            if (idx < CHUNK_F4) {
                ((float4*)s_pred)[idx] = pc[idx];
                ((float4*)s_tgt)[idx]  = tc[idx];
            }
        }
        __syncthreads();

        // ---- consume: thread t owns element (c*1024 + t) entirely ----
        const float* pe = s_pred + t * 9;   // stride 9 coprime to 32 banks
        const float* te = s_tgt  + t * 9;
        float p0 = pe[0], p1 = pe[1], p2 = pe[2], p3 = pe[3], p4 = pe[4],
              p5 = pe[5], p6 = pe[6], p7 = pe[7], p8 = pe[8];
        float t0 = te[0], t1 = te[1], t2 = te[2], t3 = te[3], t4 = te[4],
              t5 = te[5], t6 = te[6], t7 = te[7], t8 = te[8];

        bool valid = (t8 > 0.5f);
        float fm = valid ? 1.f : 0.f;
        coord_s += fm * (fabsf(p0 - t0) + fabsf(p1 - t1) + fabsf(p2 - t2) +
                         fabsf(p3 - t3) + fabsf(p4 - t4) + fabsf(p5 - t5));
        width_s += fm * (fabsf(p6 - t6) + fabsf(p7 - t7));
        nval_s  += fm;

        float pc8 = fminf(fmaxf(p8, EPSV), 1.0f - EPSV);
        val_s += -(t8 * __logf(pc8) + (1.0f - t8) * __logf(1.0f - pc8));

        const int m = c * CHUNK + t;
        s_p4[m] = p4;
        s_p5[m] = p5;
        unsigned long long bal = __ballot(valid);
        if (lane == 0) s_words[c * 16 + wave] = bal;
    }
    __syncthreads();

    // ---- continuity: next-valid bit-scan over full row ----
    float cont_s = 0.f;
    #pragma unroll
    for (int p = 0; p < 4; ++p) {
        const int m   = p * 1024 + t;
        const int w   = m >> 6;
        const int bit = m & 63;
        unsigned long long wv = s_words[w];
        if ((wv >> bit) & 1ULL) {
            unsigned long long mask = wv & ((bit == 63) ? 0ULL : (~0ULL << (bit + 1)));
            int nxt = -1;
            if (mask) {
                nxt = (w << 6) + __builtin_ctzll(mask);
            } else {
                for (int w2 = w + 1; w2 < (M_DIM / 64); ++w2) {
                    unsigned long long mw = s_words[w2];
                    if (mw) { nxt = (w2 << 6) + __builtin_ctzll(mw); break; }
                }
            }
            if (nxt >= 0) {
                cont_s += 0.5f * (fabsf(s_p4[m] - s_p4[nxt]) +
                                  fabsf(s_p5[m] - s_p5[nxt]));
            }
        }
    }

    // ---- block reduction of 6 partials; per-block slot write (no atomics) ----
    float vals[6] = {coord_s, width_s, val_s, nval_s, cont_s, recon_s};
    #pragma unroll
    for (int i = 0; i < 6; ++i) {
        float v = vals[i];
        #pragma unroll
        for (int off = 32; off > 0; off >>= 1) v += __shfl_down(v, off, 64);
        vals[i] = v;
    }
    if (lane == 0) {
        #pragma unroll
        for (int i = 0; i < 6; ++i) s_red[wave][i] = vals[i];
    }
    __syncthreads();
    if (t == 0) {
        float acc[6] = {0.f, 0.f, 0.f, 0.f, 0.f, 0.f};
        for (int wv = 0; wv < 16; ++wv)
            #pragma unroll
            for (int i = 0; i < 6; ++i) acc[i] += s_red[wv][i];
        float* r = blk_out + b * 8;
        #pragma unroll
        for (int i = 0; i < 6; ++i) r[i] = acc[i];
    }
}

__global__ __launch_bounds__(256) void finalize_kernel(
    const float* __restrict__ ws, float* __restrict__ out)
{
    const int t = threadIdx.x;
    const float* rb = ws + t * 8;
    float v[6];
    #pragma unroll
    for (int i = 0; i < 6; ++i) v[i] = rb[i];

    __shared__ float sred[4][6];
    int lane = t & 63, wave = t >> 6;
    #pragma unroll
    for (int i = 0; i < 6; ++i) {
        float x = v[i];
        #pragma unroll
        for (int off = 32; off > 0; off >>= 1) x += __shfl_down(x, off, 64);
        v[i] = x;
    }
    if (lane == 0)
        #pragma unroll
        for (int i = 0; i < 6; ++i) sred[wave][i] = v[i];
    __syncthreads();
    if (t == 0) {
        double a[6];
        #pragma unroll
        for (int i = 0; i < 6; ++i)
            a[i] = (double)sred[0][i] + (double)sred[1][i] +
                   (double)sred[2][i] + (double)sred[3][i];
        double coord_num = a[0], width_num = a[1], val_sum = a[2],
               nv = a[3], cont = a[4], recon = a[5];

        double coord = (nv > 0.0) ? coord_num / fmax(nv * 6.0, 1.0) : 0.0;
        double width = (nv > 0.0) ? width_num / fmax(nv * 2.0, 1.0) : 0.0;
        double validity = val_sum / ((double)B_DIM * (double)M_DIM);
        double contl    = cont / (double)B_DIM;
        double reconl   = recon / ((double)B_DIM * 128.0 * 128.0);

        out[0] = (float)(coord + width + 2.0 * validity +
                         0.2 * contl + 0.1 * reconl);
    }
}

extern "C" void kernel_launch(void* const* d_in, const int* in_sizes, int n_in,
                              void* d_out, int out_size, void* d_ws, size_t ws_size,
                              hipStream_t stream) {
    const float* pred = (const float*)d_in[0];
    const float* tgt  = (const float*)d_in[1];
    const float* rec  = (const float*)d_in[2];
    const float* img  = (const float*)d_in[3];
    float* ws = (float*)d_ws;

    fused_loss_kernel<<<B_DIM, THREADS, 0, stream>>>(
        (const float4*)pred, (const float4*)tgt,
        (const float4*)rec, (const float4*)img, ws);
    finalize_kernel<<<1, 256, 0, stream>>>(ws, (float*)d_out);
}